// Round 11
// baseline (470.560 us; speedup 1.0000x reference)
//
#include <hip/hip_runtime.h>

#define NTOK 4096
#define DIMC 1024
#define HEADS 12
#define DH 8
#define QSCALE 0.35355339059327373f   /* 8^-0.5 */
#define LOG2E  1.4426950408889634f
#define LN2    0.6931471805599453f
#define QPRE   (QSCALE * LOG2E)       /* fold log2e into q prescale */

typedef float f4 __attribute__((ext_vector_type(4)));
typedef float f2 __attribute__((ext_vector_type(2)));

// ws layout (floats):
//   Q:  [h][n][8]        (pre-scaled by QPRE), offset 0,    393216
//   K:  [h][16][8][256]  chunk-tiled SoA,      offset KOFF, 393216
//   T:  [h][4][n]        per-seg row totals,   offset TOFF, 196608  (3.93 MB total)
#define KOFF (HEADS * NTOK * DH)
#define TOFF (2 * KOFF)

// ---------------- Kernel 1: proj = x @ W^T -> q (AoS, scaled), k (tiled) ---
__global__ __launch_bounds__(256) void k1_proj(const float* __restrict__ x,
                                               const float* __restrict__ W,
                                               float* __restrict__ qk) {
    __shared__ float xs[8 * 1028];
    const int t = threadIdx.x;
    const int row0 = blockIdx.x * 8;

    const f4* x4 = (const f4*)(x + (size_t)row0 * DIMC);
    #pragma unroll
    for (int i = 0; i < 8; ++i) {
        int f = t + i * 256;
        int r = f >> 8;
        int c4 = f & 255;
        f4 v = x4[f];
        *(f4*)(&xs[r * 1028 + c4 * 4]) = v;
    }
    __syncthreads();

    const int g  = t >> 2;
    const int rg = t & 3;

    f2 acc[2][3];
    #pragma unroll
    for (int a = 0; a < 2; ++a)
        #pragma unroll
        for (int m = 0; m < 3; ++m) acc[a][m] = (f2)(0.f);

    const float* w0 = W + (size_t)(3 * g) * DIMC;
    #pragma unroll 2
    for (int c = 0; c < DIMC; c += 4) {
        f4 w[3];
        #pragma unroll
        for (int m = 0; m < 3; ++m)
            w[m] = *(const f4*)(w0 + (size_t)m * DIMC + c);
        #pragma unroll
        for (int a = 0; a < 2; ++a) {
            f4 xv = *(const f4*)(&xs[(rg * 2 + a) * 1028 + c]);
            #pragma unroll
            for (int m = 0; m < 3; ++m) {
                acc[a][m] = __builtin_elementwise_fma(xv.xy, w[m].xy, acc[a][m]);
                acc[a][m] = __builtin_elementwise_fma(xv.zw, w[m].zw, acc[a][m]);
            }
        }
    }

    #pragma unroll
    for (int m = 0; m < 3; ++m) {
        int o   = 3 * g + m;
        int qkf = (o >= 96) ? 1 : 0;
        int oo  = o - 96 * qkf;
        int h   = oo >> 3;
        int d   = oo & 7;
        #pragma unroll
        for (int a = 0; a < 2; ++a) {
            int n = row0 + rg * 2 + a;
            float v = acc[a][m].x + acc[a][m].y;
            if (!qkf) {
                qk[((size_t)h * NTOK + n) * DH + d] = v * QPRE;
            } else {
                qk[KOFF + (((size_t)h * 16 + (n >> 8)) * DH + d) * 256 + (n & 255)] = v;
            }
        }
    }
}

__device__ __forceinline__ float lsig2(float u) {
    // logsigmoid in log2 units: min(u,0) - log2(1 + 2^-|u|)
    float mn = fminf(u, 0.f);
    float z  = __builtin_amdgcn_exp2f(-fabsf(u));
    return mn - __builtin_amdgcn_logf(1.f + z);
}

// ---------------- Kernel A: per-(row, seg) totals; lane = row --------------
// grid 768 = (h, ib); 4 waves = 4 segs of 1024 j each. T in log2 units.
__global__ __launch_bounds__(256) void kA_totals(const float* __restrict__ qk,
                                                 float* __restrict__ T) {
    const int blk  = blockIdx.x;
    const int h    = blk >> 6;
    const int ib   = blk & 63;
    const int t    = threadIdx.x;
    const int lane = t & 63;
    const int s    = t >> 6;
    const int i    = ib * 64 + lane;        // this lane's row

    const float* qp = qk + ((size_t)h * NTOK + i) * DH;
    float q[8];
    #pragma unroll
    for (int d = 0; d < 8; ++d) q[d] = qp[d];

    float sum = 0.f;
    const int jlo = s * 1024;
    int jhi = ib * 64 + 63;                 // j < max row in block
    if (jhi > jlo + 1024) jhi = jlo + 1024;

    if (jhi > jlo) {
        for (int j0 = ((jhi - 1) & ~3); j0 >= jlo; j0 -= 4) {
            const float* kt = qk + KOFF + ((size_t)h * 16 + (j0 >> 8)) * 2048 + (j0 & 255);
            f2 A = (f2)(0.f), B = (f2)(0.f);
            #pragma unroll
            for (int d = 0; d < 8; ++d) {
                f4 kv = *(const f4*)(kt + d * 256);     // uniform addr -> broadcast
                A = __builtin_elementwise_fma(kv.xy, (f2)(q[d]), A);
                B = __builtin_elementwise_fma(kv.zw, (f2)(q[d]), B);
            }
            float g0 = (j0 + 0 < i) ? lsig2(A.x) : 0.f;
            float g1 = (j0 + 1 < i) ? lsig2(A.y) : 0.f;
            float g2 = (j0 + 2 < i) ? lsig2(B.x) : 0.f;
            float g3 = (j0 + 3 < i) ? lsig2(B.y) : 0.f;
            sum += g3; sum += g2; sum += g1; sum += g0;   // descending order
        }
    }
    T[TOFF - TOFF + ((size_t)h * 4 + s) * NTOK + i] = sum;  // T base passed directly
}

// ---------------- Kernel B: lane = row, per-lane carry, tiled dump ---------
// grid 3072 = (h, ib, s); 64 threads (1 wave). Each block: 16 j-tiles of 64.
__global__ __launch_bounds__(64) void kB_gates(const float* __restrict__ qk,
                                               const float* __restrict__ T,
                                               float* __restrict__ out) {
    const int blk  = blockIdx.x;
    const int s    = blk & 3;
    const int ib   = (blk >> 2) & 63;
    const int h    = blk >> 8;
    const int lane = threadIdx.x;
    const int r    = ib * 64 + lane;        // this lane's row

    __shared__ float tile[64 * 68];         // stride 68 floats (16B-aligned rows)

    const float* qp = qk + ((size_t)h * NTOK + r) * DH;
    float q[8];
    #pragma unroll
    for (int d = 0; d < 8; ++d) q[d] = qp[d];

    // carry entering this segment = suffix of later-segment totals (log2 units)
    float carry = 0.f;
    #pragma unroll
    for (int s2 = 3; s2 >= 1; --s2)
        if (s2 > s) carry += T[((size_t)h * 4 + s2) * NTOK + r];

    float* orow0 = out + ((size_t)h * NTOK + ib * 64) * NTOK;
    const f4 z = (f4)(0.f);

    for (int jb = s * 16 + 15; jb >= s * 16; --jb) {
        if (jb > ib) {
            // strictly-upper tile: zeros, direct row-major burst stores
            #pragma unroll
            for (int rr = 0; rr < 16; ++rr) {
                int row = rr * 4 + (lane >> 4);
                int c4  = (lane & 15) * 4;
                __builtin_nontemporal_store(z,
                    (f4*)(orow0 + (size_t)row * NTOK + jb * 64 + c4));
            }
        } else {
            const bool diag = (jb == ib);
            const float* kt = qk + KOFF + ((size_t)h * 16 + (jb >> 2)) * 2048 + (jb & 3) * 64;

            for (int jf = 15; jf >= 0; --jf) {
                const int j0 = jb * 64 + jf * 4;
                const float* kp = kt + jf * 4;
                f2 A = (f2)(0.f), B = (f2)(0.f);
                #pragma unroll
                for (int d = 0; d < 8; ++d) {
                    f4 kv = *(const f4*)(kp + d * 256);   // uniform addr -> broadcast
                    A = __builtin_elementwise_fma(kv.xy, (f2)(q[d]), A);
                    B = __builtin_elementwise_fma(kv.zw, (f2)(q[d]), B);
                }
                float g0, g1, g2, g3;
                if (diag) {
                    g0 = (j0 + 0 < r) ? lsig2(A.x) : 0.f;
                    g1 = (j0 + 1 < r) ? lsig2(A.y) : 0.f;
                    g2 = (j0 + 2 < r) ? lsig2(B.x) : 0.f;
                    g3 = (j0 + 3 < r) ? lsig2(B.y) : 0.f;
                } else {
                    g0 = lsig2(A.x); g1 = lsig2(A.y);
                    g2 = lsig2(B.x); g3 = lsig2(B.y);
                }
                // per-lane reverse cumsum, exact reference order
                float v3 = g3 + carry;
                float v2 = g2 + v3;
                float v1 = g1 + v2;
                float v0 = g0 + v1;
                carry = v0;
                f4 v = {v0 * LN2, v1 * LN2, v2 * LN2, v3 * LN2};
                *(f4*)(&tile[lane * 68 + jf * 4]) = v;
            }
            __syncthreads();
            // dump tile row-major: 4 rows x 256B per instr
            #pragma unroll
            for (int rr = 0; rr < 16; ++rr) {
                int row = rr * 4 + (lane >> 4);
                int c4  = (lane & 15) * 4;
                f4 v = *(const f4*)(&tile[row * 68 + c4]);
                __builtin_nontemporal_store(v,
                    (f4*)(orow0 + (size_t)row * NTOK + jb * 64 + c4));
            }
            __syncthreads();
        }
    }
}

extern "C" void kernel_launch(void* const* d_in, const int* in_sizes, int n_in,
                              void* d_out, int out_size, void* d_ws, size_t ws_size,
                              hipStream_t stream) {
    const float* x = (const float*)d_in[0];
    const float* W = (const float*)d_in[1];
    float* out = (float*)d_out;
    float* qk  = (float*)d_ws;               // 3.93 MB scratch
    float* T   = qk + TOFF;

    hipLaunchKernelGGL(k1_proj, dim3(NTOK / 8), dim3(256), 0, stream, x, W, qk);
    hipLaunchKernelGGL(kA_totals, dim3(HEADS * 64), dim3(256), 0, stream, qk, T);
    hipLaunchKernelGGL(kB_gates, dim3(HEADS * 64 * 4), dim3(64), 0, stream, qk, T, out);
}

// Round 12
// 204.086 us; speedup vs baseline: 2.3057x; 2.3057x over previous
//
#include <hip/hip_runtime.h>

#define NTOK 4096
#define DIMC 1024
#define HEADS 12
#define DH 8
#define QSCALE 0.35355339059327373f   /* 8^-0.5 */
#define LOG2E  1.4426950408889634f
#define LN2    0.6931471805599453f
#define QPRE   (QSCALE * LOG2E)       /* fold log2e into q prescale */

typedef float f4 __attribute__((ext_vector_type(4)));
typedef float f2 __attribute__((ext_vector_type(2)));

// ws layout (floats):
//   Q:  [h][n][8]        (pre-scaled by QPRE), offset 0,    12*4096*8
//   K:  [h][16][8][256]  chunk-tiled SoA,      offset KOFF, 12*8*4096
#define KOFF (HEADS * NTOK * DH)

// ---------------- Kernel 1: proj = x @ W^T -> q (AoS, scaled), k (tiled) ---
__global__ __launch_bounds__(256) void k1_proj(const float* __restrict__ x,
                                               const float* __restrict__ W,
                                               float* __restrict__ qk) {
    __shared__ float xs[8 * 1028];         // pad 1024->1028 breaks bank aliasing
    const int t = threadIdx.x;
    const int row0 = blockIdx.x * 8;

    const f4* x4 = (const f4*)(x + (size_t)row0 * DIMC);
    #pragma unroll
    for (int i = 0; i < 8; ++i) {
        int f = t + i * 256;
        int r = f >> 8;
        int c4 = f & 255;
        f4 v = x4[f];
        *(f4*)(&xs[r * 1028 + c4 * 4]) = v;
    }
    __syncthreads();

    const int g  = t >> 2;                 // 0..63 -> owns o = 3g..3g+2
    const int rg = t & 3;                  // owns rows rg*2 .. rg*2+1

    f2 acc[2][3];
    #pragma unroll
    for (int a = 0; a < 2; ++a)
        #pragma unroll
        for (int m = 0; m < 3; ++m) acc[a][m] = (f2)(0.f);

    const float* w0 = W + (size_t)(3 * g) * DIMC;
    #pragma unroll 2
    for (int c = 0; c < DIMC; c += 4) {
        f4 w[3];
        #pragma unroll
        for (int m = 0; m < 3; ++m)
            w[m] = *(const f4*)(w0 + (size_t)m * DIMC + c);
        #pragma unroll
        for (int a = 0; a < 2; ++a) {
            f4 xv = *(const f4*)(&xs[(rg * 2 + a) * 1028 + c]);
            #pragma unroll
            for (int m = 0; m < 3; ++m) {
                acc[a][m] = __builtin_elementwise_fma(xv.xy, w[m].xy, acc[a][m]);
                acc[a][m] = __builtin_elementwise_fma(xv.zw, w[m].zw, acc[a][m]);
            }
        }
    }

    #pragma unroll
    for (int m = 0; m < 3; ++m) {
        int o   = 3 * g + m;
        int qkf = (o >= 96) ? 1 : 0;
        int oo  = o - 96 * qkf;
        int h   = oo >> 3;
        int d   = oo & 7;
        #pragma unroll
        for (int a = 0; a < 2; ++a) {
            int n = row0 + rg * 2 + a;
            float v = acc[a][m].x + acc[a][m].y;
            if (!qkf) {
                qk[((size_t)h * NTOK + n) * DH + d] = v * QPRE;        // Q AoS
            } else {
                qk[KOFF + (((size_t)h * 16 + (n >> 8)) * DH + d) * 256 + (n & 255)] = v;
            }
        }
    }
}

// ---------------- Kernel 2: 1 row per wave, 4 KB ascending store bursts ----
__device__ __forceinline__ float lsig2(float u) {
    // logsigmoid in log2 units: min(u,0) - log2(1 + 2^-|u|)   (u = s*log2e)
    float mn = fminf(u, 0.f);
    float z  = __builtin_amdgcn_exp2f(-fabsf(u));   // -|u| is a free modifier
    return mn - __builtin_amdgcn_logf(1.f + z);     // v_log_f32 = log2
}

__global__ __launch_bounds__(512) void k2_gates(const float* __restrict__ qk,
                                                float* __restrict__ out) {
    const int bid  = blockIdx.x;
    const int h    = bid >> 9;              // 512 blocks per head
    const int i0   = (bid & 511) << 3;      // 8 rows per block, 1 per wave
    const int t    = threadIdx.x;
    const int lane = t & 63;
    const int wid  = t >> 6;                // 0..7
    const int r    = i0 + wid;              // this wave's row

    const float* qp = qk + ((size_t)h * NTOK + r) * DH;
    float q[8];
    #pragma unroll
    for (int d = 0; d < 8; ++d) q[d] = qp[d];

    const float* kh = qk + KOFF + (size_t)h * (16 * DH * 256) + 4 * lane;
    float* o = out + ((size_t)h * NTOK + r) * NTOK;

    const int cb = r >> 8;                  // boundary 256-chunk
    const int bb = cb >> 2;                 // boundary 1024-big-chunk

    const f4 z = (f4)(0.f);

    // ---- big-chunks entirely above the diagonal: 4 KB ascending zero bursts
    for (int b = 3; b > bb; --b) {
        float* ob = o + b * 1024 + 4 * lane;
        #pragma unroll
        for (int sub = 0; sub < 4; ++sub)
            __builtin_nontemporal_store(z, (f4*)(ob + sub * 256));
    }

    // ---- big-chunks with compute: process subchunks descending (carry),
    //      then emit one ascending 4 KB back-to-back burst ------------------
    float carry = 0.f;
    for (int b = bb; b >= 0; --b) {
        f4 ov[4];
        #pragma unroll
        for (int sub = 3; sub >= 0; --sub) {
            const int cc = b * 4 + sub;
            if (cc > cb) { ov[sub] = z; continue; }       // only when b == bb

            const float* kc = kh + (size_t)cc * 2048;
            f4 kv[8];
            #pragma unroll
            for (int d = 0; d < 8; ++d) kv[d] = *(const f4*)(kc + d * 256);

            f2 A = (f2)(0.f), B = (f2)(0.f);
            #pragma unroll
            for (int d = 0; d < 8; ++d) {
                A = __builtin_elementwise_fma(kv[d].xy, (f2)(q[d]), A);
                B = __builtin_elementwise_fma(kv[d].zw, (f2)(q[d]), B);
            }

            const int j0 = cc * 256 + 4 * lane;
            float g0, g1, g2, g3;
            if (cc == cb) {                  // boundary: mask j < r
                g0 = (j0 + 0 < r) ? lsig2(A.x) : 0.f;
                g1 = (j0 + 1 < r) ? lsig2(A.y) : 0.f;
                g2 = (j0 + 2 < r) ? lsig2(B.x) : 0.f;
                g3 = (j0 + 3 < r) ? lsig2(B.y) : 0.f;
            } else {                         // interior: all j < r
                g0 = lsig2(A.x); g1 = lsig2(A.y);
                g2 = lsig2(B.x); g3 = lsig2(B.y);
            }

            g2 += g3; g1 += g2; g0 += g1;    // local reverse suffix
            const float tot = g0;
            float s = tot;
            #pragma unroll
            for (int off = 1; off < 64; off <<= 1) {
                float v = __shfl_down(s, off, 64);
                if (lane + off < 64) s += v;
            }
            const float base = (s - tot) + carry;
            carry += __builtin_amdgcn_readfirstlane(s);

            f4 gv = {g0, g1, g2, g3};
            ov[sub] = (gv + base) * LN2;
        }

        // ascending, back-to-back 4 KB burst for this row
        float* ob = o + b * 1024 + 4 * lane;
        #pragma unroll
        for (int sub = 0; sub < 4; ++sub)
            __builtin_nontemporal_store(ov[sub], (f4*)(ob + sub * 256));
    }
}

extern "C" void kernel_launch(void* const* d_in, const int* in_sizes, int n_in,
                              void* d_out, int out_size, void* d_ws, size_t ws_size,
                              hipStream_t stream) {
    const float* x = (const float*)d_in[0];
    const float* W = (const float*)d_in[1];
    float* out = (float*)d_out;
    float* qk  = (float*)d_ws;               // 3 MB scratch

    hipLaunchKernelGGL(k1_proj, dim3(NTOK / 8), dim3(256), 0, stream, x, W, qk);
    hipLaunchKernelGGL(k2_gates, dim3(HEADS * NTOK / 8), dim3(512), 0, stream, qk, out);
}